// Round 1
// 699.086 us; speedup vs baseline: 1.0608x; 1.0608x over previous
//
#include <hip/hip_runtime.h>
#include <stdint.h>

#define B_ 16
#define C_ 768
#define N_ 4096
#define HEADS_ 12

typedef __attribute__((ext_vector_type(4))) float f32x4;
typedef __attribute__((ext_vector_type(8))) short s16x8;

__device__ __forceinline__ ushort f2bf(float f){
  union { float f; uint32_t u; } v; v.f = f;
  uint32_t u = v.u;
  uint32_t r = (u + 0x7fffu + ((u >> 16) & 1u)) >> 16;
  return (ushort)r;
}
__device__ __forceinline__ float bf2f(ushort h){
  union { uint32_t u; float f; } v; v.u = ((uint32_t)h) << 16;
  return v.f;
}

// async global->LDS, 16B per lane; lds dest must be wave-uniform base (HW adds lane*16)
__device__ __forceinline__ void gload16(const ushort* g, ushort* l){
  __builtin_amdgcn_global_load_lds(
      (__attribute__((address_space(1))) void*)(g),
      (__attribute__((address_space(3))) void*)(l), 16, 0, 0);
}

// ---------------- convert fp32 -> bf16 (Wqkv) ----------------
__global__ __launch_bounds__(256) void k_convert(const float* __restrict__ src,
                                                 ushort* __restrict__ dst, int n){
  int i = (blockIdx.x * 256 + threadIdx.x) * 4;
  if (i < n){
    float4 v = *(const float4*)(src + i);
    ushort4 u;
    u.x = f2bf(v.x); u.y = f2bf(v.y); u.z = f2bf(v.z); u.w = f2bf(v.w);
    *(ushort4*)(dst + i) = u;
  }
}

// ---------------- transpose+convert x[b][c][n] -> xT[b][n][c] bf16 ----------------
__global__ __launch_bounds__(256) void k_transpose(const float* __restrict__ x,
                                                   ushort* __restrict__ xT){
  __shared__ ushort tile[64][72];
  int b = blockIdx.z;
  int n0 = blockIdx.x * 64;
  int k0 = blockIdx.y * 64;
  int t = threadIdx.x;
  const float* xb = x + (size_t)b * C_ * N_;
  #pragma unroll
  for (int p = 0; p < 4; ++p){
    int krow = (t >> 4) + p * 16;
    int nn = (t & 15) * 4;
    float4 v = *(const float4*)(xb + (size_t)(k0 + krow) * N_ + n0 + nn);
    tile[nn + 0][krow] = f2bf(v.x);
    tile[nn + 1][krow] = f2bf(v.y);
    tile[nn + 2][krow] = f2bf(v.z);
    tile[nn + 3][krow] = f2bf(v.w);
  }
  __syncthreads();
  ushort* dst = xT + (size_t)b * N_ * C_;
  #pragma unroll
  for (int p = 0; p < 4; ++p){
    int nrow = (t >> 4) + p * 16;
    int kk = (t & 15) * 4;
    ushort4 u = *(ushort4*)&tile[nrow][kk];
    *(ushort4*)(dst + (size_t)(n0 + nrow) * C_ + k0 + kk) = u;
  }
}

// ---------------- GEMM1: w[b][n][c'] = sum_k xT[b][n][k] * Wq[c'][k], + colnorm2 ----
#define BM 128
#define BN 128
#define BK 64

__global__ __launch_bounds__(256, 2) void k_gemm1(const ushort* __restrict__ xT,
                                                  const ushort* __restrict__ wq,
                                                  ushort* __restrict__ w,
                                                  float* __restrict__ colnorm2){
  __shared__ ushort As[BM * BK];   // [row][64] linear, 16 KB
  __shared__ ushort Bs[BN * BK];
  int b = blockIdx.z;
  int n0 = blockIdx.x * BM;
  int c0 = blockIdx.y * BN;
  int t = threadIdx.x;
  int lane = t & 63, wv = t >> 6;
  int wm = wv >> 1, wn = wv & 1;
  int col = lane & 15, quad = lane >> 4;
  const ushort* Ag = xT + (size_t)b * N_ * C_ + (size_t)n0 * C_;
  const ushort* Bg = wq + (size_t)c0 * C_;
  int srow = lane >> 3;            // row within 8-row group
  int sch  = (lane & 7) * 8;       // ushort chunk within row
  f32x4 acc[4][4] = {};
  for (int kt = 0; kt < C_; kt += BK){
    #pragma unroll
    for (int c = 0; c < 4; ++c){
      int rb8 = wv * 32 + c * 8;        // wave-uniform base row
      int r = rb8 + srow;
      gload16(Ag + (size_t)r * C_ + kt + sch, &As[rb8 * 64]);
      gload16(Bg + (size_t)r * C_ + kt + sch, &Bs[rb8 * 64]);
    }
    __syncthreads();   // compiler drains vmcnt(0) before s_barrier
    #pragma unroll
    for (int ks = 0; ks < 2; ++ks){
      s16x8 af[4], bfr[4];
      #pragma unroll
      for (int mt = 0; mt < 4; ++mt)
        af[mt] = *(const s16x8*)&As[(wm * 64 + mt * 16 + col) * 64 + ks * 32 + quad * 8];
      #pragma unroll
      for (int nt = 0; nt < 4; ++nt)
        bfr[nt] = *(const s16x8*)&Bs[(wn * 64 + nt * 16 + col) * 64 + ks * 32 + quad * 8];
      #pragma unroll
      for (int mt = 0; mt < 4; ++mt)
        #pragma unroll
        for (int nt = 0; nt < 4; ++nt)
          acc[mt][nt] = __builtin_amdgcn_mfma_f32_16x16x32_bf16(af[mt], bfr[nt], acc[mt][nt], 0, 0, 0);
    }
    __syncthreads();
  }
  // epilogue: D[row=n][col=c']; store bf16 w and accumulate column sums of squares
  ushort* wb = w + (size_t)b * N_ * C_;
  #pragma unroll
  for (int nt = 0; nt < 4; ++nt){
    int cc = c0 + wn * 64 + nt * 16 + col;
    float ss = 0.f;
    #pragma unroll
    for (int mt = 0; mt < 4; ++mt){
      #pragma unroll
      for (int r = 0; r < 4; ++r){
        int nn = n0 + wm * 64 + mt * 16 + quad * 4 + r;
        float v = acc[mt][nt][r];
        wb[(size_t)nn * C_ + cc] = f2bf(v);
        ss += v * v;
      }
    }
    ss += __shfl_xor(ss, 16);
    ss += __shfl_xor(ss, 32);
    if (quad == 0) atomicAdd(colnorm2 + b * C_ + cc, ss);
  }
}

// ---------------- stats: softmax over heads, S/T reductions, w *= Pi in place ------
__global__ __launch_bounds__(256) void k_stats(ushort* __restrict__ w,
                                               const float* __restrict__ colnorm2,
                                               const float* __restrict__ temp,
                                               float* __restrict__ S,
                                               float* __restrict__ T){
  int b = blockIdx.y;
  int chunk = blockIdx.x;          // 0..31
  int t = threadIdx.x;
  int lane = t & 63, wv = t >> 6;
  float invcn[HEADS_], tmp[HEADS_], S_loc[HEADS_], T_loc[HEADS_];
  #pragma unroll
  for (int j = 0; j < HEADS_; ++j){
    float cn = colnorm2[b * C_ + j * 64 + lane];
    invcn[j] = 1.0f / fmaxf(cn, 1e-24f);
    tmp[j] = temp[j];
    S_loc[j] = 0.f; T_loc[j] = 0.f;
  }
  ushort* wb = w + (size_t)b * N_ * C_;
  for (int it = 0; it < 32; ++it){
    int n = chunk * 128 + wv * 32 + it;
    ushort* row = wb + (size_t)n * C_;
    float fj[HEADS_], r[HEADS_];
    #pragma unroll
    for (int j = 0; j < HEADS_; ++j){
      float f = bf2f(row[j * 64 + lane]);
      fj[j] = f;
      r[j] = f * f * invcn[j];
    }
    #pragma unroll
    for (int j = 0; j < HEADS_; ++j){
      #pragma unroll
      for (int off = 1; off < 64; off <<= 1)
        r[j] += __shfl_xor(r[j], off);
    }
    float m = -1e30f;
    #pragma unroll
    for (int j = 0; j < HEADS_; ++j){ r[j] *= tmp[j]; m = fmaxf(m, r[j]); }
    float se = 0.f, p[HEADS_];
    #pragma unroll
    for (int j = 0; j < HEADS_; ++j){ p[j] = __expf(r[j] - m); se += p[j]; }
    float inv = 1.0f / se;
    #pragma unroll
    for (int j = 0; j < HEADS_; ++j){
      p[j] *= inv;                      // p[j] is wave-uniform
      S_loc[j] += p[j];
      T_loc[j] += p[j] * fj[j] * fj[j];
      row[j * 64 + lane] = f2bf(fj[j] * p[j]);   // w *= Pi, in place
    }
  }
  #pragma unroll
  for (int j = 0; j < HEADS_; ++j){
    atomicAdd(T + b * C_ + j * 64 + lane, T_loc[j]);
    if (lane == j) atomicAdd(S + b * HEADS_ + j, S_loc[j]);
  }
}

// ---------------- WoutS[b][c'][k] = -Wout[c'][k] * attn[b][k], attn = s/(s+t) ------
__global__ __launch_bounds__(256) void k_scale_wout(const float* __restrict__ Wout,
                                                    const float* __restrict__ S,
                                                    const float* __restrict__ T,
                                                    ushort* __restrict__ woS,
                                                    int b0){
  int bz = blockIdx.y; int b = b0 + bz;
  int i = (blockIdx.x * 256 + threadIdx.x) * 4;    // grid.x*256*4 == C_*C_
  int k = i % C_;
  float s = S[b * HEADS_ + (k >> 6)] + 1e-8f;
  float4 t4 = *(const float4*)(T + b * C_ + k);
  float4 v = *(const float4*)(Wout + i);
  ushort4 u;
  u.x = f2bf(-v.x * s / (s + t4.x));
  u.y = f2bf(-v.y * s / (s + t4.y));
  u.z = f2bf(-v.z * s / (s + t4.z));
  u.w = f2bf(-v.w * s / (s + t4.w));
  *(ushort4*)(woS + (size_t)bz * C_ * C_ + i) = u;
}

// ---------------- GEMM2: out[b][c'][n] = sum_k WoutS[b][c'][k] * wp[b][n][k] -------
__global__ __launch_bounds__(256, 2) void k_gemm2(const ushort* __restrict__ wp,
                                                  const ushort* __restrict__ woS,
                                                  float* __restrict__ out,
                                                  int b0){
  __shared__ ushort As[BM * BK];   // WoutS rows [c'][64]
  __shared__ ushort Bs[BN * BK];   // wp rows [n][64]
  int bz = blockIdx.z; int b = b0 + bz;
  int c0 = blockIdx.x * BM;
  int n0 = blockIdx.y * BN;
  int t = threadIdx.x;
  int lane = t & 63, wv = t >> 6;
  int wm = wv >> 1, wn = wv & 1;
  int col = lane & 15, quad = lane >> 4;
  const ushort* Ag = woS + (size_t)bz * C_ * C_ + (size_t)c0 * C_;
  const ushort* Bg = wp + (size_t)b * N_ * C_ + (size_t)n0 * C_;
  int srow = lane >> 3;
  int sch  = (lane & 7) * 8;
  f32x4 acc[4][4] = {};
  for (int kt = 0; kt < C_; kt += BK){
    #pragma unroll
    for (int c = 0; c < 4; ++c){
      int rb8 = wv * 32 + c * 8;
      int r = rb8 + srow;
      gload16(Ag + (size_t)r * C_ + kt + sch, &As[rb8 * 64]);
      gload16(Bg + (size_t)r * C_ + kt + sch, &Bs[rb8 * 64]);
    }
    __syncthreads();
    #pragma unroll
    for (int ks = 0; ks < 2; ++ks){
      s16x8 af[4], bfr[4];
      #pragma unroll
      for (int mt = 0; mt < 4; ++mt)
        af[mt] = *(const s16x8*)&As[(wm * 64 + mt * 16 + col) * 64 + ks * 32 + quad * 8];
      #pragma unroll
      for (int nt = 0; nt < 4; ++nt)
        bfr[nt] = *(const s16x8*)&Bs[(wn * 64 + nt * 16 + col) * 64 + ks * 32 + quad * 8];
      #pragma unroll
      for (int mt = 0; mt < 4; ++mt)
        #pragma unroll
        for (int nt = 0; nt < 4; ++nt)
          acc[mt][nt] = __builtin_amdgcn_mfma_f32_16x16x32_bf16(af[mt], bfr[nt], acc[mt][nt], 0, 0, 0);
    }
    __syncthreads();
  }
  // epilogue: D[row=c'][col=n] -> out[b][c'][n], lane-coalesced along n
  #pragma unroll
  for (int mt = 0; mt < 4; ++mt){
    #pragma unroll
    for (int nt = 0; nt < 4; ++nt){
      int nn = n0 + wn * 64 + nt * 16 + col;
      #pragma unroll
      for (int r = 0; r < 4; ++r){
        int cc = c0 + wm * 64 + mt * 16 + quad * 4 + r;
        out[((size_t)b * C_ + cc) * N_ + nn] = acc[mt][nt][r];
      }
    }
  }
}

extern "C" void kernel_launch(void* const* d_in, const int* in_sizes, int n_in,
                              void* d_out, int out_size, void* d_ws, size_t ws_size,
                              hipStream_t stream){
  const float* x    = (const float*)d_in[0];
  const float* Wqkv = (const float*)d_in[1];
  const float* Wout = (const float*)d_in[2];
  const float* temp = (const float*)d_in[3];
  float* out = (float*)d_out;
  char* ws = (char*)d_ws;

  const size_t sz_w     = (size_t)B_ * N_ * C_ * sizeof(ushort);   // 100,663,296
  const size_t sz_wt    = (size_t)C_ * C_ * sizeof(ushort);        // 1,179,648
  const size_t sz_stats = (size_t)(2 * B_ * C_ + B_ * HEADS_) * sizeof(float); // 99,072

  ushort* w_buf    = (ushort*)ws;                       // w, then w*Pi in place
  float*  colnorm2 = (float*)(ws + sz_w);
  float*  S_       = colnorm2 + B_ * C_;
  float*  T_       = S_ + B_ * HEADS_;
  ushort* woS      = (ushort*)(ws + sz_w + sz_stats);   // per-batch -Wout*attn (bf16)

  // xT and wq_b live in d_out (both dead before GEMM2 writes d_out)
  ushort* xT   = (ushort*)d_out;
  ushort* wq_b = (ushort*)((char*)d_out + sz_w);

  hipMemsetAsync(colnorm2, 0, sz_stats, stream);
  k_convert<<<576, 256, 0, stream>>>(Wqkv, wq_b, C_ * C_);
  k_transpose<<<dim3(N_ / 64, C_ / 64, B_), 256, 0, stream>>>(x, xT);
  k_gemm1<<<dim3(N_ / BM, C_ / BN, B_), 256, 0, stream>>>(xT, wq_b, w_buf, colnorm2);
  k_stats<<<dim3(32, B_), 256, 0, stream>>>(w_buf, colnorm2, temp, S_, T_);

  const size_t need_full = sz_w + sz_stats + (size_t)B_ * sz_wt;   // ~119.6 MB
  if (ws_size >= need_full){
    k_scale_wout<<<dim3(C_ * C_ / 1024, B_), 256, 0, stream>>>(Wout, S_, T_, woS, 0);
    k_gemm2<<<dim3(C_ / BM, N_ / BN, B_), 256, 0, stream>>>(w_buf, woS, out, 0);
  } else {
    // fits the previously-proven footprint: groups of 4 batches, single woS buffer
    for (int b0 = 0; b0 < B_; b0 += 4){
      k_scale_wout<<<dim3(C_ * C_ / 1024, 4), 256, 0, stream>>>(Wout, S_, T_, woS, b0);
      k_gemm2<<<dim3(C_ / BM, N_ / BN, 4), 256, 0, stream>>>(w_buf, woS, out, b0);
    }
  }
}

// Round 2
// 662.154 us; speedup vs baseline: 1.1200x; 1.0558x over previous
//
#include <hip/hip_runtime.h>
#include <stdint.h>

#define B_ 16
#define C_ 768
#define N_ 4096
#define HEADS_ 12

typedef __attribute__((ext_vector_type(4))) float f32x4;
typedef __attribute__((ext_vector_type(8))) short s16x8;

__device__ __forceinline__ ushort f2bf(float f){
  union { float f; uint32_t u; } v; v.f = f;
  uint32_t u = v.u;
  uint32_t r = (u + 0x7fffu + ((u >> 16) & 1u)) >> 16;
  return (ushort)r;
}
__device__ __forceinline__ float bf2f(ushort h){
  union { uint32_t u; float f; } v; v.u = ((uint32_t)h) << 16;
  return v.f;
}

// async global->LDS, 16B per lane; lds dest must be wave-uniform base (HW adds lane*16)
__device__ __forceinline__ void gload16(const ushort* g, ushort* l){
  __builtin_amdgcn_global_load_lds(
      (__attribute__((address_space(1))) void*)(g),
      (__attribute__((address_space(3))) void*)(l), 16, 0, 0);
}

// ---------------- convert fp32 -> bf16 (Wqkv) ----------------
__global__ __launch_bounds__(256) void k_convert(const float* __restrict__ src,
                                                 ushort* __restrict__ dst, int n){
  int i = (blockIdx.x * 256 + threadIdx.x) * 4;
  if (i < n){
    float4 v = *(const float4*)(src + i);
    ushort4 u;
    u.x = f2bf(v.x); u.y = f2bf(v.y); u.z = f2bf(v.z); u.w = f2bf(v.w);
    *(ushort4*)(dst + i) = u;
  }
}

// ---------------- transpose+convert x[b][c][n] -> xT[b][n][c] bf16 ----------------
__global__ __launch_bounds__(256) void k_transpose(const float* __restrict__ x,
                                                   ushort* __restrict__ xT){
  __shared__ ushort tile[64][72];
  int b = blockIdx.z;
  int n0 = blockIdx.x * 64;
  int k0 = blockIdx.y * 64;
  int t = threadIdx.x;
  const float* xb = x + (size_t)b * C_ * N_;
  #pragma unroll
  for (int p = 0; p < 4; ++p){
    int krow = (t >> 4) + p * 16;
    int nn = (t & 15) * 4;
    float4 v = *(const float4*)(xb + (size_t)(k0 + krow) * N_ + n0 + nn);
    tile[nn + 0][krow] = f2bf(v.x);
    tile[nn + 1][krow] = f2bf(v.y);
    tile[nn + 2][krow] = f2bf(v.z);
    tile[nn + 3][krow] = f2bf(v.w);
  }
  __syncthreads();
  ushort* dst = xT + (size_t)b * N_ * C_;
  #pragma unroll
  for (int p = 0; p < 4; ++p){
    int nrow = (t >> 4) + p * 16;
    int kk = (t & 15) * 4;
    ushort4 u = *(ushort4*)&tile[nrow][kk];
    *(ushort4*)(dst + (size_t)(n0 + nrow) * C_ + k0 + kk) = u;
  }
}

// ---------------- GEMM1: w[b][n][c'] = sum_k xT[b][n][k] * Wq[c'][k], + colnorm2 ----
#define BM 128
#define BN 128
#define BK 64

__global__ __launch_bounds__(256, 2) void k_gemm1(const ushort* __restrict__ xT,
                                                  const ushort* __restrict__ wq,
                                                  ushort* __restrict__ w,
                                                  float* __restrict__ colnorm2){
  __shared__ ushort As[BM * BK];   // [row][64] linear, 16 KB
  __shared__ ushort Bs[BN * BK];
  int b = blockIdx.z;
  int n0 = blockIdx.x * BM;
  int c0 = blockIdx.y * BN;
  int t = threadIdx.x;
  int lane = t & 63, wv = t >> 6;
  int wm = wv >> 1, wn = wv & 1;
  int col = lane & 15, quad = lane >> 4;
  const ushort* Ag = xT + (size_t)b * N_ * C_ + (size_t)n0 * C_;
  const ushort* Bg = wq + (size_t)c0 * C_;
  int srow = lane >> 3;            // row within 8-row group
  int sch  = (lane & 7) * 8;       // ushort chunk within row
  f32x4 acc[4][4] = {};
  for (int kt = 0; kt < C_; kt += BK){
    #pragma unroll
    for (int c = 0; c < 4; ++c){
      int rb8 = wv * 32 + c * 8;        // wave-uniform base row
      int r = rb8 + srow;
      gload16(Ag + (size_t)r * C_ + kt + sch, &As[rb8 * 64]);
      gload16(Bg + (size_t)r * C_ + kt + sch, &Bs[rb8 * 64]);
    }
    __syncthreads();   // compiler drains vmcnt(0) before s_barrier
    #pragma unroll
    for (int ks = 0; ks < 2; ++ks){
      s16x8 af[4], bfr[4];
      #pragma unroll
      for (int mt = 0; mt < 4; ++mt)
        af[mt] = *(const s16x8*)&As[(wm * 64 + mt * 16 + col) * 64 + ks * 32 + quad * 8];
      #pragma unroll
      for (int nt = 0; nt < 4; ++nt)
        bfr[nt] = *(const s16x8*)&Bs[(wn * 64 + nt * 16 + col) * 64 + ks * 32 + quad * 8];
      #pragma unroll
      for (int mt = 0; mt < 4; ++mt)
        #pragma unroll
        for (int nt = 0; nt < 4; ++nt)
          acc[mt][nt] = __builtin_amdgcn_mfma_f32_16x16x32_bf16(af[mt], bfr[nt], acc[mt][nt], 0, 0, 0);
    }
    __syncthreads();
  }
  // epilogue: D[row=n][col=c']; store bf16 w and accumulate column sums of squares
  ushort* wb = w + (size_t)b * N_ * C_;
  #pragma unroll
  for (int nt = 0; nt < 4; ++nt){
    int cc = c0 + wn * 64 + nt * 16 + col;
    float ss = 0.f;
    #pragma unroll
    for (int mt = 0; mt < 4; ++mt){
      #pragma unroll
      for (int r = 0; r < 4; ++r){
        int nn = n0 + wm * 64 + mt * 16 + quad * 4 + r;
        float v = acc[mt][nt][r];
        wb[(size_t)nn * C_ + cc] = f2bf(v);
        ss += v * v;
      }
    }
    ss += __shfl_xor(ss, 16);
    ss += __shfl_xor(ss, 32);
    if (quad == 0) atomicAdd(colnorm2 + b * C_ + cc, ss);
  }
}

// ---------------- stats: softmax over heads, S/T reductions, w *= Pi in place ------
// Lane L-chunks: lane owns ushort4 chunks c = lane + 64*L (L=0..2) of the 768-wide row.
// head(c) = 4L + (lane>>4); cols (lane&15)*4 .. +3. Per-head reduce = 16-lane reduce.
__global__ __launch_bounds__(256) void k_stats(ushort* __restrict__ w,
                                               const float* __restrict__ colnorm2,
                                               const float* __restrict__ temp,
                                               float* __restrict__ S,
                                               float* __restrict__ T){
  int b = blockIdx.y;
  int chunk = blockIdx.x;          // 0..63
  int t = threadIdx.x;
  int lane = t & 63, wv = t >> 6;
  int g = lane >> 4;               // lane group 0..3
  int colb = (lane & 15) * 4;      // column base within head

  float invcn[3][4], tval[3][4], T_loc[3][4], S_own[3];
  #pragma unroll
  for (int L = 0; L < 3; ++L){
    float4 cn = *(const float4*)(colnorm2 + b * C_ + (4 * L + g) * 64 + colb);
    invcn[L][0] = 1.0f / fmaxf(cn.x, 1e-24f);
    invcn[L][1] = 1.0f / fmaxf(cn.y, 1e-24f);
    invcn[L][2] = 1.0f / fmaxf(cn.z, 1e-24f);
    invcn[L][3] = 1.0f / fmaxf(cn.w, 1e-24f);
    #pragma unroll
    for (int k = 0; k < 4; ++k) tval[L][k] = temp[4 * L + (g ^ k)];
    #pragma unroll
    for (int i = 0; i < 4; ++i) T_loc[L][i] = 0.f;
    S_own[L] = 0.f;
  }

  ushort* wb = w + (size_t)b * N_ * C_;
  for (int it = 0; it < 16; ++it){
    int n = chunk * 64 + wv * 16 + it;
    ushort* row = wb + (size_t)n * C_;
    float f[3][4], v[3][4], part[3];
    #pragma unroll
    for (int L = 0; L < 3; ++L){
      ushort4 u = *(const ushort4*)(row + (lane + 64 * L) * 4);
      f[L][0] = bf2f(u.x); f[L][1] = bf2f(u.y);
      f[L][2] = bf2f(u.z); f[L][3] = bf2f(u.w);
      part[L] = 0.f;
      #pragma unroll
      for (int i = 0; i < 4; ++i){
        v[L][i] = f[L][i] * f[L][i];
        part[L] += v[L][i] * invcn[L][i];
      }
    }
    // 16-lane (within-group) reduce -> per-head sum in each group's lanes
    #pragma unroll
    for (int L = 0; L < 3; ++L){
      #pragma unroll
      for (int off = 1; off < 16; off <<= 1)
        part[L] += __shfl_xor(part[L], off);
    }
    // gather all 12 head-values (heads 4L + g^k via xor-16k), apply temp
    float val[3][4];
    #pragma unroll
    for (int L = 0; L < 3; ++L){
      val[L][0] = tval[L][0] * part[L];
      val[L][1] = tval[L][1] * __shfl_xor(part[L], 16);
      val[L][2] = tval[L][2] * __shfl_xor(part[L], 32);
      val[L][3] = tval[L][3] * __shfl_xor(part[L], 48);
    }
    float m = val[0][0];
    #pragma unroll
    for (int L = 0; L < 3; ++L)
      #pragma unroll
      for (int k = 0; k < 4; ++k) m = fmaxf(m, val[L][k]);
    float se = 0.f, e0[3];
    #pragma unroll
    for (int L = 0; L < 3; ++L){
      #pragma unroll
      for (int k = 0; k < 4; ++k){
        float e = __expf(val[L][k] - m);
        se += e;
        if (k == 0) e0[L] = e;
      }
    }
    float inv = 1.0f / se;
    #pragma unroll
    for (int L = 0; L < 3; ++L){
      float p = e0[L] * inv;          // Pi for this lane's head, uniform in group
      S_own[L] += p;
      ushort4 s4;
      T_loc[L][0] += p * v[L][0];  s4.x = f2bf(f[L][0] * p);
      T_loc[L][1] += p * v[L][1];  s4.y = f2bf(f[L][1] * p);
      T_loc[L][2] += p * v[L][2];  s4.z = f2bf(f[L][2] * p);
      T_loc[L][3] += p * v[L][3];  s4.w = f2bf(f[L][3] * p);
      *(ushort4*)(row + (lane + 64 * L) * 4) = s4;   // w *= Pi in place
    }
  }
  #pragma unroll
  for (int L = 0; L < 3; ++L){
    #pragma unroll
    for (int i = 0; i < 4; ++i)
      atomicAdd(T + b * C_ + (4 * L + g) * 64 + colb + i, T_loc[L][i]);
    if ((lane & 15) == 0) atomicAdd(S + b * HEADS_ + 4 * L + g, S_own[L]);
  }
}

// ---------------- WoutS[b][c'][k] = -Wout[c'][k] * attn[b][k], attn = s/(s+t) ------
__global__ __launch_bounds__(256) void k_scale_wout(const float* __restrict__ Wout,
                                                    const float* __restrict__ S,
                                                    const float* __restrict__ T,
                                                    ushort* __restrict__ woS,
                                                    int b0){
  int bz = blockIdx.y; int b = b0 + bz;
  int i = (blockIdx.x * 256 + threadIdx.x) * 4;    // grid.x*256*4 == C_*C_
  int k = i % C_;
  float s = S[b * HEADS_ + (k >> 6)] + 1e-8f;
  float4 t4 = *(const float4*)(T + b * C_ + k);
  float4 v = *(const float4*)(Wout + i);
  ushort4 u;
  u.x = f2bf(-v.x * s / (s + t4.x));
  u.y = f2bf(-v.y * s / (s + t4.y));
  u.z = f2bf(-v.z * s / (s + t4.z));
  u.w = f2bf(-v.w * s / (s + t4.w));
  *(ushort4*)(woS + (size_t)bz * C_ * C_ + i) = u;
}

// ---------------- GEMM2: out[b][c'][n] = sum_k WoutS[b][c'][k] * wp[b][n][k] -------
// XCD-aware bijective swizzle: 6 consecutive logical blocks share a wp B-panel ->
// land on the same XCD L2 (grid total divisible by 8 on both launch paths).
__global__ __launch_bounds__(256, 2) void k_gemm2(const ushort* __restrict__ wp,
                                                  const ushort* __restrict__ woS,
                                                  float* __restrict__ out,
                                                  int b0){
  __shared__ ushort As[BM * BK];   // WoutS rows [c'][64]
  __shared__ ushort Bs[BN * BK];   // wp rows [n][64]
  int nwg = gridDim.x * gridDim.y * gridDim.z;
  int hid = blockIdx.x + gridDim.x * (blockIdx.y + gridDim.y * blockIdx.z);
  int lid = (hid & 7) * (nwg >> 3) + (hid >> 3);
  int xb = lid % 6;                // c-block (fastest: panel sharers contiguous)
  int yb = (lid / 6) % 32;         // n-block
  int zb = lid / 192;              // batch within dispatch
  int b = b0 + zb;
  int c0 = xb * BM;
  int n0 = yb * BN;
  int t = threadIdx.x;
  int lane = t & 63, wv = t >> 6;
  int wm = wv >> 1, wn = wv & 1;
  int col = lane & 15, quad = lane >> 4;
  const ushort* Ag = woS + (size_t)zb * C_ * C_ + (size_t)c0 * C_;
  const ushort* Bg = wp + (size_t)b * N_ * C_ + (size_t)n0 * C_;
  int srow = lane >> 3;
  int sch  = (lane & 7) * 8;
  f32x4 acc[4][4] = {};
  for (int kt = 0; kt < C_; kt += BK){
    #pragma unroll
    for (int c = 0; c < 4; ++c){
      int rb8 = wv * 32 + c * 8;
      int r = rb8 + srow;
      gload16(Ag + (size_t)r * C_ + kt + sch, &As[rb8 * 64]);
      gload16(Bg + (size_t)r * C_ + kt + sch, &Bs[rb8 * 64]);
    }
    __syncthreads();
    #pragma unroll
    for (int ks = 0; ks < 2; ++ks){
      s16x8 af[4], bfr[4];
      #pragma unroll
      for (int mt = 0; mt < 4; ++mt)
        af[mt] = *(const s16x8*)&As[(wm * 64 + mt * 16 + col) * 64 + ks * 32 + quad * 8];
      #pragma unroll
      for (int nt = 0; nt < 4; ++nt)
        bfr[nt] = *(const s16x8*)&Bs[(wn * 64 + nt * 16 + col) * 64 + ks * 32 + quad * 8];
      #pragma unroll
      for (int mt = 0; mt < 4; ++mt)
        #pragma unroll
        for (int nt = 0; nt < 4; ++nt)
          acc[mt][nt] = __builtin_amdgcn_mfma_f32_16x16x32_bf16(af[mt], bfr[nt], acc[mt][nt], 0, 0, 0);
    }
    __syncthreads();
  }
  // epilogue: D[row=c'][col=n] -> out[b][c'][n], lane-coalesced along n
  #pragma unroll
  for (int mt = 0; mt < 4; ++mt){
    #pragma unroll
    for (int nt = 0; nt < 4; ++nt){
      int nn = n0 + wn * 64 + nt * 16 + col;
      #pragma unroll
      for (int r = 0; r < 4; ++r){
        int cc = c0 + wm * 64 + mt * 16 + quad * 4 + r;
        out[((size_t)b * C_ + cc) * N_ + nn] = acc[mt][nt][r];
      }
    }
  }
}

extern "C" void kernel_launch(void* const* d_in, const int* in_sizes, int n_in,
                              void* d_out, int out_size, void* d_ws, size_t ws_size,
                              hipStream_t stream){
  const float* x    = (const float*)d_in[0];
  const float* Wqkv = (const float*)d_in[1];
  const float* Wout = (const float*)d_in[2];
  const float* temp = (const float*)d_in[3];
  float* out = (float*)d_out;
  char* ws = (char*)d_ws;

  const size_t sz_w     = (size_t)B_ * N_ * C_ * sizeof(ushort);   // 100,663,296
  const size_t sz_wt    = (size_t)C_ * C_ * sizeof(ushort);        // 1,179,648
  const size_t sz_stats = (size_t)(2 * B_ * C_ + B_ * HEADS_) * sizeof(float); // 99,072

  ushort* w_buf    = (ushort*)ws;                       // w, then w*Pi in place
  float*  colnorm2 = (float*)(ws + sz_w);
  float*  S_       = colnorm2 + B_ * C_;
  float*  T_       = S_ + B_ * HEADS_;
  ushort* woS      = (ushort*)(ws + sz_w + sz_stats);   // per-batch -Wout*attn (bf16)

  // xT and wq_b live in d_out (both dead before GEMM2 writes d_out)
  ushort* xT   = (ushort*)d_out;
  ushort* wq_b = (ushort*)((char*)d_out + sz_w);

  hipMemsetAsync(colnorm2, 0, sz_stats, stream);
  k_convert<<<576, 256, 0, stream>>>(Wqkv, wq_b, C_ * C_);
  k_transpose<<<dim3(N_ / 64, C_ / 64, B_), 256, 0, stream>>>(x, xT);
  k_gemm1<<<dim3(N_ / BM, C_ / BN, B_), 256, 0, stream>>>(xT, wq_b, w_buf, colnorm2);
  k_stats<<<dim3(64, B_), 256, 0, stream>>>(w_buf, colnorm2, temp, S_, T_);

  const size_t need_full = sz_w + sz_stats + (size_t)B_ * sz_wt;   // ~119.6 MB
  if (ws_size >= need_full){
    k_scale_wout<<<dim3(C_ * C_ / 1024, B_), 256, 0, stream>>>(Wout, S_, T_, woS, 0);
    k_gemm2<<<dim3(C_ / BM, N_ / BN, B_), 256, 0, stream>>>(w_buf, woS, out, 0);
  } else {
    // fits the previously-proven footprint: groups of 4 batches, single woS buffer
    for (int b0 = 0; b0 < B_; b0 += 4){
      k_scale_wout<<<dim3(C_ * C_ / 1024, 4), 256, 0, stream>>>(Wout, S_, T_, woS, b0);
      k_gemm2<<<dim3(C_ / BM, N_ / BN, 4), 256, 0, stream>>>(w_buf, woS, out, b0);
    }
  }
}

// Round 3
// 629.955 us; speedup vs baseline: 1.1772x; 1.0511x over previous
//
#include <hip/hip_runtime.h>
#include <stdint.h>

#define B_ 16
#define C_ 768
#define N_ 4096
#define HEADS_ 12

typedef __attribute__((ext_vector_type(4))) float f32x4;
typedef __attribute__((ext_vector_type(8))) short s16x8;

__device__ __forceinline__ ushort f2bf(float f){
  union { float f; uint32_t u; } v; v.f = f;
  uint32_t u = v.u;
  uint32_t r = (u + 0x7fffu + ((u >> 16) & 1u)) >> 16;
  return (ushort)r;
}
__device__ __forceinline__ float bf2f(ushort h){
  union { uint32_t u; float f; } v; v.u = ((uint32_t)h) << 16;
  return v.f;
}

// async global->LDS, 16B per lane; lds dest must be wave-uniform base (HW adds lane*16)
__device__ __forceinline__ void gload16(const ushort* g, ushort* l){
  __builtin_amdgcn_global_load_lds(
      (__attribute__((address_space(1))) void*)(g),
      (__attribute__((address_space(3))) void*)(l), 16, 0, 0);
}

// ---------------- convert fp32 -> bf16 (Wqkv) ----------------
__global__ __launch_bounds__(256) void k_convert(const float* __restrict__ src,
                                                 ushort* __restrict__ dst, int n){
  int i = (blockIdx.x * 256 + threadIdx.x) * 4;
  if (i < n){
    float4 v = *(const float4*)(src + i);
    ushort4 u;
    u.x = f2bf(v.x); u.y = f2bf(v.y); u.z = f2bf(v.z); u.w = f2bf(v.w);
    *(ushort4*)(dst + i) = u;
  }
}

// ---------------- transpose+convert x[b][c][n] -> xT[b][n][c] bf16 ----------------
__global__ __launch_bounds__(256) void k_transpose(const float* __restrict__ x,
                                                   ushort* __restrict__ xT){
  __shared__ ushort tile[64][72];
  int b = blockIdx.z;
  int n0 = blockIdx.x * 64;
  int k0 = blockIdx.y * 64;
  int t = threadIdx.x;
  const float* xb = x + (size_t)b * C_ * N_;
  #pragma unroll
  for (int p = 0; p < 4; ++p){
    int krow = (t >> 4) + p * 16;
    int nn = (t & 15) * 4;
    float4 v = *(const float4*)(xb + (size_t)(k0 + krow) * N_ + n0 + nn);
    tile[nn + 0][krow] = f2bf(v.x);
    tile[nn + 1][krow] = f2bf(v.y);
    tile[nn + 2][krow] = f2bf(v.z);
    tile[nn + 3][krow] = f2bf(v.w);
  }
  __syncthreads();
  ushort* dst = xT + (size_t)b * N_ * C_;
  #pragma unroll
  for (int p = 0; p < 4; ++p){
    int nrow = (t >> 4) + p * 16;
    int kk = (t & 15) * 4;
    ushort4 u = *(ushort4*)&tile[nrow][kk];
    *(ushort4*)(dst + (size_t)(n0 + nrow) * C_ + k0 + kk) = u;
  }
}

// ---------------- GEMM1: w[b][n][c'] = sum_k xT[b][n][k] * Wq[c'][k], + colnorm2 ----
#define BM 128
#define BN 128
#define BK 64

__global__ __launch_bounds__(256, 2) void k_gemm1(const ushort* __restrict__ xT,
                                                  const ushort* __restrict__ wq,
                                                  ushort* __restrict__ w,
                                                  float* __restrict__ colnorm2){
  __shared__ ushort As[BM * BK];   // [row][64] linear, 16 KB
  __shared__ ushort Bs[BN * BK];
  int b = blockIdx.z;
  int n0 = blockIdx.x * BM;
  int c0 = blockIdx.y * BN;
  int t = threadIdx.x;
  int lane = t & 63, wv = t >> 6;
  int wm = wv >> 1, wn = wv & 1;
  int col = lane & 15, quad = lane >> 4;
  const ushort* Ag = xT + (size_t)b * N_ * C_ + (size_t)n0 * C_;
  const ushort* Bg = wq + (size_t)c0 * C_;
  int srow = lane >> 3;            // row within 8-row group
  int sch  = (lane & 7) * 8;       // ushort chunk within row
  f32x4 acc[4][4] = {};
  for (int kt = 0; kt < C_; kt += BK){
    #pragma unroll
    for (int c = 0; c < 4; ++c){
      int rb8 = wv * 32 + c * 8;        // wave-uniform base row
      int r = rb8 + srow;
      gload16(Ag + (size_t)r * C_ + kt + sch, &As[rb8 * 64]);
      gload16(Bg + (size_t)r * C_ + kt + sch, &Bs[rb8 * 64]);
    }
    __syncthreads();   // compiler drains vmcnt(0) before s_barrier
    #pragma unroll
    for (int ks = 0; ks < 2; ++ks){
      s16x8 af[4], bfr[4];
      #pragma unroll
      for (int mt = 0; mt < 4; ++mt)
        af[mt] = *(const s16x8*)&As[(wm * 64 + mt * 16 + col) * 64 + ks * 32 + quad * 8];
      #pragma unroll
      for (int nt = 0; nt < 4; ++nt)
        bfr[nt] = *(const s16x8*)&Bs[(wn * 64 + nt * 16 + col) * 64 + ks * 32 + quad * 8];
      #pragma unroll
      for (int mt = 0; mt < 4; ++mt)
        #pragma unroll
        for (int nt = 0; nt < 4; ++nt)
          acc[mt][nt] = __builtin_amdgcn_mfma_f32_16x16x32_bf16(af[mt], bfr[nt], acc[mt][nt], 0, 0, 0);
    }
    __syncthreads();
  }
  // epilogue: D[row=n][col=c']; store bf16 w and accumulate column sums of squares
  ushort* wb = w + (size_t)b * N_ * C_;
  #pragma unroll
  for (int nt = 0; nt < 4; ++nt){
    int cc = c0 + wn * 64 + nt * 16 + col;
    float ss = 0.f;
    #pragma unroll
    for (int mt = 0; mt < 4; ++mt){
      #pragma unroll
      for (int r = 0; r < 4; ++r){
        int nn = n0 + wm * 64 + mt * 16 + quad * 4 + r;
        float v = acc[mt][nt][r];
        wb[(size_t)nn * C_ + cc] = f2bf(v);
        ss += v * v;
      }
    }
    ss += __shfl_xor(ss, 16);
    ss += __shfl_xor(ss, 32);
    if (quad == 0) atomicAdd(colnorm2 + b * C_ + cc, ss);
  }
}

// ---------------- stats: softmax over heads, S/T reductions, w *= Pi in place ------
// Lane owns ushort4 chunks c = lane + 64*L (L=0..2); head(c) = 4L + (lane>>4).
// SW-pipelined: next row's loads issue before current row's compute/store, so the
// in-place-store alias no longer serializes iterations on load latency.
__global__ __launch_bounds__(256) void k_stats(ushort* __restrict__ w,
                                               const float* __restrict__ colnorm2,
                                               const float* __restrict__ temp,
                                               float* __restrict__ S,
                                               float* __restrict__ T){
  __shared__ float Tred[4][768];
  __shared__ float Sred[4][12];
  int b = blockIdx.y;
  int chunk = blockIdx.x;          // 0..127
  int t = threadIdx.x;
  int lane = t & 63, wv = t >> 6;
  int g = lane >> 4;               // lane group 0..3
  int colb = (lane & 15) * 4;      // column base within head

  float invcn[3][4], tval[3][4], T_loc[3][4], S_own[3];
  #pragma unroll
  for (int L = 0; L < 3; ++L){
    float4 cn = *(const float4*)(colnorm2 + b * C_ + (4 * L + g) * 64 + colb);
    invcn[L][0] = 1.0f / fmaxf(cn.x, 1e-24f);
    invcn[L][1] = 1.0f / fmaxf(cn.y, 1e-24f);
    invcn[L][2] = 1.0f / fmaxf(cn.z, 1e-24f);
    invcn[L][3] = 1.0f / fmaxf(cn.w, 1e-24f);
    #pragma unroll
    for (int k = 0; k < 4; ++k) tval[L][k] = temp[4 * L + (g ^ k)];
    #pragma unroll
    for (int i = 0; i < 4; ++i) T_loc[L][i] = 0.f;
    S_own[L] = 0.f;
  }

  ushort* wb = w + (size_t)b * N_ * C_;
  int n0 = chunk * 32 + wv * 8;    // 8 rows per wave
  ushort4 u[3], un[3];
  {
    ushort* row0 = wb + (size_t)n0 * C_;
    #pragma unroll
    for (int L = 0; L < 3; ++L) u[L] = *(const ushort4*)(row0 + (lane + 64 * L) * 4);
  }
  #pragma unroll
  for (int it = 0; it < 8; ++it){
    ushort* row = wb + (size_t)(n0 + it) * C_;
    if (it < 7){
      ushort* rn = row + C_;
      #pragma unroll
      for (int L = 0; L < 3; ++L) un[L] = *(const ushort4*)(rn + (lane + 64 * L) * 4);
    }
    float f[3][4], v[3][4], part[3];
    #pragma unroll
    for (int L = 0; L < 3; ++L){
      f[L][0] = bf2f(u[L].x); f[L][1] = bf2f(u[L].y);
      f[L][2] = bf2f(u[L].z); f[L][3] = bf2f(u[L].w);
      part[L] = 0.f;
      #pragma unroll
      for (int i = 0; i < 4; ++i){
        v[L][i] = f[L][i] * f[L][i];
        part[L] += v[L][i] * invcn[L][i];
      }
    }
    // 16-lane (within-group) reduce -> per-head sum in each group's lanes
    #pragma unroll
    for (int L = 0; L < 3; ++L){
      #pragma unroll
      for (int off = 1; off < 16; off <<= 1)
        part[L] += __shfl_xor(part[L], off);
    }
    // gather all 12 head-values (heads 4L + g^k via xor-16k), apply temp
    float val[3][4];
    #pragma unroll
    for (int L = 0; L < 3; ++L){
      val[L][0] = tval[L][0] * part[L];
      val[L][1] = tval[L][1] * __shfl_xor(part[L], 16);
      val[L][2] = tval[L][2] * __shfl_xor(part[L], 32);
      val[L][3] = tval[L][3] * __shfl_xor(part[L], 48);
    }
    float m = val[0][0];
    #pragma unroll
    for (int L = 0; L < 3; ++L)
      #pragma unroll
      for (int k = 0; k < 4; ++k) m = fmaxf(m, val[L][k]);
    float se = 0.f, e0[3];
    #pragma unroll
    for (int L = 0; L < 3; ++L){
      #pragma unroll
      for (int k = 0; k < 4; ++k){
        float e = __expf(val[L][k] - m);
        se += e;
        if (k == 0) e0[L] = e;
      }
    }
    float inv = 1.0f / se;
    #pragma unroll
    for (int L = 0; L < 3; ++L){
      float p = e0[L] * inv;          // Pi for this lane's head, uniform in group
      S_own[L] += p;
      ushort4 s4;
      T_loc[L][0] += p * v[L][0];  s4.x = f2bf(f[L][0] * p);
      T_loc[L][1] += p * v[L][1];  s4.y = f2bf(f[L][1] * p);
      T_loc[L][2] += p * v[L][2];  s4.z = f2bf(f[L][2] * p);
      T_loc[L][3] += p * v[L][3];  s4.w = f2bf(f[L][3] * p);
      *(ushort4*)(row + (lane + 64 * L) * 4) = s4;   // w *= Pi in place
    }
    #pragma unroll
    for (int L = 0; L < 3; ++L) u[L] = un[L];
  }
  // block-level reduction of T/S partials, then one atomic per column
  #pragma unroll
  for (int L = 0; L < 3; ++L){
    *(f32x4*)&Tred[wv][(4 * L + g) * 64 + colb] =
        (f32x4){T_loc[L][0], T_loc[L][1], T_loc[L][2], T_loc[L][3]};
    if ((lane & 15) == 0) Sred[wv][4 * L + g] = S_own[L];
  }
  __syncthreads();
  #pragma unroll
  for (int q = 0; q < 3; ++q){
    int c = t + 256 * q;
    float s = Tred[0][c] + Tred[1][c] + Tred[2][c] + Tred[3][c];
    atomicAdd(T + b * C_ + c, s);
  }
  if (t < 12) atomicAdd(S + b * HEADS_ + t,
                        Sred[0][t] + Sred[1][t] + Sred[2][t] + Sred[3][t]);
}

// ---------------- WoutS[b][c'][k] = -Wout[c'][k] * attn[b][k], attn = s/(s+t) ------
__global__ __launch_bounds__(256) void k_scale_wout(const float* __restrict__ Wout,
                                                    const float* __restrict__ S,
                                                    const float* __restrict__ T,
                                                    ushort* __restrict__ woS,
                                                    int b0){
  int bz = blockIdx.y; int b = b0 + bz;
  int i = (blockIdx.x * 256 + threadIdx.x) * 4;    // grid.x*256*4 == C_*C_
  int k = i % C_;
  float s = S[b * HEADS_ + (k >> 6)] + 1e-8f;
  float4 t4 = *(const float4*)(T + b * C_ + k);
  float4 v = *(const float4*)(Wout + i);
  ushort4 u;
  u.x = f2bf(-v.x * s / (s + t4.x));
  u.y = f2bf(-v.y * s / (s + t4.y));
  u.z = f2bf(-v.z * s / (s + t4.z));
  u.w = f2bf(-v.w * s / (s + t4.w));
  *(ushort4*)(woS + (size_t)bz * C_ * C_ + i) = u;
}

// ---------------- GEMM2: out[b][c'][n] = sum_k WoutS[b][c'][k] * wp[b][n][k] -------
// XCD-aware bijective swizzle: 6 consecutive logical blocks share a wp B-panel ->
// land on the same XCD L2 (grid total divisible by 8 on both launch paths).
__global__ __launch_bounds__(256, 2) void k_gemm2(const ushort* __restrict__ wp,
                                                  const ushort* __restrict__ woS,
                                                  float* __restrict__ out,
                                                  int b0){
  __shared__ ushort As[BM * BK];   // WoutS rows [c'][64]
  __shared__ ushort Bs[BN * BK];   // wp rows [n][64]
  int nwg = gridDim.x * gridDim.y * gridDim.z;
  int hid = blockIdx.x + gridDim.x * (blockIdx.y + gridDim.y * blockIdx.z);
  int lid = (hid & 7) * (nwg >> 3) + (hid >> 3);
  int xb = lid % 6;                // c-block (fastest: panel sharers contiguous)
  int yb = (lid / 6) % 32;         // n-block
  int zb = lid / 192;              // batch within dispatch
  int b = b0 + zb;
  int c0 = xb * BM;
  int n0 = yb * BN;
  int t = threadIdx.x;
  int lane = t & 63, wv = t >> 6;
  int wm = wv >> 1, wn = wv & 1;
  int col = lane & 15, quad = lane >> 4;
  const ushort* Ag = woS + (size_t)zb * C_ * C_ + (size_t)c0 * C_;
  const ushort* Bg = wp + (size_t)b * N_ * C_ + (size_t)n0 * C_;
  int srow = lane >> 3;
  int sch  = (lane & 7) * 8;
  f32x4 acc[4][4] = {};
  for (int kt = 0; kt < C_; kt += BK){
    #pragma unroll
    for (int c = 0; c < 4; ++c){
      int rb8 = wv * 32 + c * 8;
      int r = rb8 + srow;
      gload16(Ag + (size_t)r * C_ + kt + sch, &As[rb8 * 64]);
      gload16(Bg + (size_t)r * C_ + kt + sch, &Bs[rb8 * 64]);
    }
    __syncthreads();
    #pragma unroll
    for (int ks = 0; ks < 2; ++ks){
      s16x8 af[4], bfr[4];
      #pragma unroll
      for (int mt = 0; mt < 4; ++mt)
        af[mt] = *(const s16x8*)&As[(wm * 64 + mt * 16 + col) * 64 + ks * 32 + quad * 8];
      #pragma unroll
      for (int nt = 0; nt < 4; ++nt)
        bfr[nt] = *(const s16x8*)&Bs[(wn * 64 + nt * 16 + col) * 64 + ks * 32 + quad * 8];
      #pragma unroll
      for (int mt = 0; mt < 4; ++mt)
        #pragma unroll
        for (int nt = 0; nt < 4; ++nt)
          acc[mt][nt] = __builtin_amdgcn_mfma_f32_16x16x32_bf16(af[mt], bfr[nt], acc[mt][nt], 0, 0, 0);
    }
    __syncthreads();
  }
  // epilogue: D[row=c'][col=n] -> out[b][c'][n], lane-coalesced along n
  #pragma unroll
  for (int mt = 0; mt < 4; ++mt){
    #pragma unroll
    for (int nt = 0; nt < 4; ++nt){
      int nn = n0 + wn * 64 + nt * 16 + col;
      #pragma unroll
      for (int r = 0; r < 4; ++r){
        int cc = c0 + wm * 64 + mt * 16 + quad * 4 + r;
        out[((size_t)b * C_ + cc) * N_ + nn] = acc[mt][nt][r];
      }
    }
  }
}

extern "C" void kernel_launch(void* const* d_in, const int* in_sizes, int n_in,
                              void* d_out, int out_size, void* d_ws, size_t ws_size,
                              hipStream_t stream){
  const float* x    = (const float*)d_in[0];
  const float* Wqkv = (const float*)d_in[1];
  const float* Wout = (const float*)d_in[2];
  const float* temp = (const float*)d_in[3];
  float* out = (float*)d_out;
  char* ws = (char*)d_ws;

  const size_t sz_w     = (size_t)B_ * N_ * C_ * sizeof(ushort);   // 100,663,296
  const size_t sz_wt    = (size_t)C_ * C_ * sizeof(ushort);        // 1,179,648
  const size_t sz_stats = (size_t)(2 * B_ * C_ + B_ * HEADS_) * sizeof(float); // 99,072

  ushort* w_buf    = (ushort*)ws;                       // w, then w*Pi in place
  float*  colnorm2 = (float*)(ws + sz_w);
  float*  S_       = colnorm2 + B_ * C_;
  float*  T_       = S_ + B_ * HEADS_;
  ushort* woS      = (ushort*)(ws + sz_w + sz_stats);   // per-batch -Wout*attn (bf16)

  // xT and wq_b live in d_out (both dead before GEMM2 writes d_out)
  ushort* xT   = (ushort*)d_out;
  ushort* wq_b = (ushort*)((char*)d_out + sz_w);

  hipMemsetAsync(colnorm2, 0, sz_stats, stream);
  k_convert<<<576, 256, 0, stream>>>(Wqkv, wq_b, C_ * C_);
  k_transpose<<<dim3(N_ / 64, C_ / 64, B_), 256, 0, stream>>>(x, xT);
  k_gemm1<<<dim3(N_ / BM, C_ / BN, B_), 256, 0, stream>>>(xT, wq_b, w_buf, colnorm2);
  k_stats<<<dim3(128, B_), 256, 0, stream>>>(w_buf, colnorm2, temp, S_, T_);

  const size_t need_full = sz_w + sz_stats + (size_t)B_ * sz_wt;   // ~119.6 MB
  if (ws_size >= need_full){
    k_scale_wout<<<dim3(C_ * C_ / 1024, B_), 256, 0, stream>>>(Wout, S_, T_, woS, 0);
    k_gemm2<<<dim3(C_ / BM, N_ / BN, B_), 256, 0, stream>>>(w_buf, woS, out, 0);
  } else {
    // fits the previously-proven footprint: groups of 4 batches, single woS buffer
    for (int b0 = 0; b0 < B_; b0 += 4){
      k_scale_wout<<<dim3(C_ * C_ / 1024, 4), 256, 0, stream>>>(Wout, S_, T_, woS, b0);
      k_gemm2<<<dim3(C_ / BM, N_ / BN, 4), 256, 0, stream>>>(w_buf, woS, out, b0);
    }
  }
}